// Round 11
// baseline (761.178 us; speedup 1.0000x reference)
//
#include <hip/hip_runtime.h>

typedef short bf16x8 __attribute__((ext_vector_type(8)));
typedef _Float16 f16x8 __attribute__((ext_vector_type(8)));
typedef float f32x4 __attribute__((ext_vector_type(4)));

__device__ __forceinline__ short f2h(float f) {
  _Float16 h = (_Float16)f;
  return __builtin_bit_cast(short, h);
}
__device__ __forceinline__ float h2f(short s) {
  return (float)__builtin_bit_cast(_Float16, s);
}

__device__ __forceinline__ void gload16(const void* g, void* lds) {
  __builtin_amdgcn_global_load_lds(
      (const __attribute__((address_space(1))) unsigned*)g,
      (__attribute__((address_space(3))) unsigned*)lds, 16, 0, 0);
}

// ---------------------------------------------------------------------------
// Fat-wave 256x256 GEMM, C = A @ B^T (f16, K contiguous), 256 thr = 4 waves,
// wave grid 2Mx2N, wave tile 128x128 (acc 8x8 frags = 256 VGPR; 1 wave/SIMD,
// __launch_bounds__(256,1) -> 512-VGPR budget). LDS-read duplication 2x2
// (64KB/32-K vs 96KB for 8-wave 2x4) -> LDS stream < MFMA floor.
// Chunk = K=64: A 256 rows x 128B (32KB) + B 32KB, swizzled col^=(row&7)<<4
// within 128B rows (round-6-measured conflict-free). 2 slots = 128KB.
// Per chunk t: barrier -> stage(t+1) [16 gloads, slot (t+1)&1: all waves'
// reads of that slot were lgkm-confirmed before they reached this barrier]
// -> vmcnt(16) [t resident; t+1 in flight across the whole chunk compute]
// -> issue 32 ds_reads (ks0+ks1) -> lgkm(15) [DS retires in order; oldest 17
// = all 16 ks0 reads done] -> 64 MFMA ks0 -> lgkm(0) -> 64 MFMA ks1.
// sched_barrier(0) after every asm wait (rule #18).
// ---------------------------------------------------------------------------
template <int K, int OMODE, int BIAS_MODE, int RES>
__global__ __launch_bounds__(256, 1) void gemmf(
    const short* __restrict__ A, int lda, long sA,
    const short* __restrict__ B, int ldb, long sB,
    void* __restrict__ Cv, int ldc, long sC,
    const float* __restrict__ bias, const float* __restrict__ resid, long sR) {
  constexpr int NT = K / 64;
  __shared__ __align__(1024) char lds[131072];  // 2 x (A 32KB + B 32KB)

  A += (size_t)blockIdx.z * sA;
  B += (size_t)blockIdx.z * sB;
  char* Cb = (char*)Cv + (size_t)blockIdx.z * sC * (OMODE == 0 ? 4 : 2);
  const float* res = resid ? resid + (size_t)blockIdx.z * sR : nullptr;

  const int tid = threadIdx.x;
  const int wid = tid >> 6, lane = tid & 63;
  const int wm = wid >> 1, wn = wid & 1;  // wave grid 2 (M) x 2 (N)
  const int fr = lane & 15, fq = lane >> 4;
  const size_t bm = (size_t)blockIdx.y * 256;
  const size_t bn = (size_t)blockIdx.x * 256;

  const char* Ag = (const char*)A;
  const char* Bg = (const char*)B;
  const size_t ldaB = (size_t)lda * 2, ldbB = (size_t)ldb * 2;

  // staging: gload i covers rows 32i + wid*8 + (lane>>3); within each 128B
  // row-chunk the lane reads col granule (lane&7)^(lane>>3) (inv-swizzle),
  // dest linear at i*4096 + wid*1024 (+lane*16 implicit).
  const int lrow = lane >> 3;
  const int scol = ((lane & 7) ^ lrow) * 16;

  // ds_read: logical (row, colgran c') at phys row*128 + (c'*16 ^ (row&7)<<4)
  const int swz = (fr & 7) << 4;
  const int aoff0 = (wm * 128 + fr) * 128 + ((fq * 16) ^ swz);           // +m*2048, ^64 for ks1
  const int boff0 = 32768 + (wn * 128 + fr) * 128 + ((fq * 16) ^ swz);   // +n*2048

  f32x4 acc[8][8];
#pragma unroll
  for (int m = 0; m < 8; m++)
#pragma unroll
    for (int n = 0; n < 8; n++) acc[m][n] = (f32x4){0.f, 0.f, 0.f, 0.f};

  auto stage = [&](int t) {
    char* s = &lds[(t & 1) * 65536];
    const size_t ktB = (size_t)t * 128;
#pragma unroll
    for (int i = 0; i < 8; ++i)
      gload16(Ag + (bm + 32 * i + wid * 8 + lrow) * ldaB + ktB + scol,
              s + i * 4096 + wid * 1024);
#pragma unroll
    for (int i = 0; i < 8; ++i)
      gload16(Bg + (bn + 32 * i + wid * 8 + lrow) * ldbB + ktB + scol,
              s + 32768 + i * 4096 + wid * 1024);
  };

  stage(0);
  for (int t = 0; t < NT; ++t) {
    __builtin_amdgcn_s_barrier();
    __builtin_amdgcn_sched_barrier(0);
    if (t + 1 < NT) {
      stage(t + 1);
      __builtin_amdgcn_sched_barrier(0);
      asm volatile("s_waitcnt vmcnt(16)");
    } else {
      asm volatile("s_waitcnt vmcnt(0)");
    }
    __builtin_amdgcn_sched_barrier(0);
    const char* s = &lds[(t & 1) * 65536];
    f16x8 a0[8], b0[8], a1[8], b1[8];
#pragma unroll
    for (int m = 0; m < 8; m++)
      a0[m] = *(const f16x8*)(s + (aoff0 + m * 2048));
#pragma unroll
    for (int n = 0; n < 8; n++)
      b0[n] = *(const f16x8*)(s + (boff0 + n * 2048));
#pragma unroll
    for (int m = 0; m < 8; m++)
      a1[m] = *(const f16x8*)(s + ((aoff0 ^ 64) + m * 2048));
#pragma unroll
    for (int n = 0; n < 8; n++)
      b1[n] = *(const f16x8*)(s + ((boff0 ^ 64) + n * 2048));
    __builtin_amdgcn_sched_barrier(0);
    asm volatile("s_waitcnt lgkmcnt(15)");  // DS in-order: all 16 ks0 retired
    __builtin_amdgcn_sched_barrier(0);
    __builtin_amdgcn_s_setprio(1);
#pragma unroll
    for (int m = 0; m < 8; m++)
#pragma unroll
      for (int n = 0; n < 8; n++)
        acc[m][n] = __builtin_amdgcn_mfma_f32_16x16x32_f16(a0[m], b0[n],
                                                           acc[m][n], 0, 0, 0);
    __builtin_amdgcn_s_setprio(0);
    __builtin_amdgcn_sched_barrier(0);
    asm volatile("s_waitcnt lgkmcnt(0)");
    __builtin_amdgcn_sched_barrier(0);
    __builtin_amdgcn_s_setprio(1);
#pragma unroll
    for (int m = 0; m < 8; m++)
#pragma unroll
      for (int n = 0; n < 8; n++)
        acc[m][n] = __builtin_amdgcn_mfma_f32_16x16x32_f16(a1[m], b1[n],
                                                           acc[m][n], 0, 0, 0);
    __builtin_amdgcn_s_setprio(0);
    __builtin_amdgcn_sched_barrier(0);
  }

#pragma unroll
  for (int m = 0; m < 8; m++) {
    const size_t row0 = bm + wm * 128 + m * 16 + fq * 4;
#pragma unroll
    for (int n = 0; n < 8; n++) {
      const size_t col = bn + wn * 128 + n * 16 + fr;
      float bcol = (BIAS_MODE == 1) ? bias[col] : 0.f;
#pragma unroll
      for (int r = 0; r < 4; r++) {
        float val = acc[m][n][r];
        const size_t row = row0 + r;
        const size_t idx = row * (size_t)ldc + col;
        if (BIAS_MODE == 1) val += bcol;
        if (BIAS_MODE == 2) val += bias[row];
        if (RES) val += res[idx];
        if (OMODE == 0)
          ((float*)Cb)[idx] = val;
        else
          ((short*)Cb)[idx] = f2h(val);
      }
    }
  }
}

__global__ __launch_bounds__(256) void cvt_f32_f16(const float* __restrict__ s,
                                                   short* __restrict__ d, int n) {
  int i = (blockIdx.x * 256 + threadIdx.x) * 8;
  if (i >= n) return;
  const float4 a = *(const float4*)(s + i);
  const float4 b = *(const float4*)(s + i + 4);
  bf16x8 o;
  o[0] = f2h(a.x); o[1] = f2h(a.y); o[2] = f2h(a.z); o[3] = f2h(a.w);
  o[4] = f2h(b.x); o[5] = f2h(b.y); o[6] = f2h(b.z); o[7] = f2h(b.w);
  *(bf16x8*)(d + i) = o;
}

// one block per row of 4096 f16 scores; fp32 softmax; in-place f16 probs
__global__ __launch_bounds__(256) void softmax_rows(short* __restrict__ S) {
  const size_t row = blockIdx.x;
  short* rp = S + row * 4096;
  const int tid = threadIdx.x;
  const int lane = tid & 63, wid = tid >> 6;
  float v[16];
#pragma unroll
  for (int c = 0; c < 2; c++) {
    bf16x8 xv = *(const bf16x8*)(rp + (c * 256 + tid) * 8);
#pragma unroll
    for (int j = 0; j < 8; j++) v[c * 8 + j] = h2f(xv[j]);
  }
  float m = v[0];
#pragma unroll
  for (int i = 1; i < 16; i++) m = fmaxf(m, v[i]);
#pragma unroll
  for (int off = 32; off >= 1; off >>= 1) m = fmaxf(m, __shfl_xor(m, off));
  __shared__ float red[8];
  if (lane == 0) red[wid] = m;
  __syncthreads();
  m = fmaxf(fmaxf(red[0], red[1]), fmaxf(red[2], red[3]));
  float s = 0.f;
#pragma unroll
  for (int i = 0; i < 16; i++) {
    v[i] = __expf(v[i] - m);
    s += v[i];
  }
#pragma unroll
  for (int off = 32; off >= 1; off >>= 1) s += __shfl_xor(s, off);
  if (lane == 0) red[4 + wid] = s;
  __syncthreads();
  s = (red[4] + red[5]) + (red[6] + red[7]);
  const float rs = 1.0f / s;
#pragma unroll
  for (int c = 0; c < 2; c++) {
    bf16x8 o;
#pragma unroll
    for (int j = 0; j < 8; j++) o[j] = f2h(v[c * 8 + j] * rs);
    *(bf16x8*)(rp + (c * 256 + tid) * 8) = o;
  }
}

extern "C" void kernel_launch(void* const* d_in, const int* in_sizes, int n_in,
                              void* d_out, int out_size, void* d_ws,
                              size_t ws_size, hipStream_t stream) {
  const float* x   = (const float*)d_in[0];
  const float* thw = (const float*)d_in[1];
  const float* thb = (const float*)d_in[2];
  const float* phw = (const float*)d_in[3];
  const float* phb = (const float*)d_in[4];
  const float* gw  = (const float*)d_in[5];
  const float* gbi = (const float*)d_in[6];
  const float* Ww  = (const float*)d_in[7];
  const float* Wb  = (const float*)d_in[8];
  float* out = (float*)d_out;

  // B=4, N=4096, D=2048, E=1024.  ws footprint 184,557,568 B (proven size)
  char* ws = (char*)d_ws;
  short* xf   = (short*)(ws);                // 67,108,864 B (16384x2048 f16)
  short* wcat = (short*)(ws + 67108864);     //  8,388,608 B (theta|phi 2048x2048)
  short* gwb  = (short*)(ws + 75497472);     //  4,194,304 B (1024x2048)
  short* wWb  = (short*)(ws + 79691776);     //  4,194,304 B (2048x1024)
  float* bc   = (float*)(ws + 83886080);     //  8,192 B (theta_b|phi_b)
  short* tpf  = (short*)(ws + 83894272);     // 67,108,864 B (theta|phi; later y)
  short* gT   = (short*)(ws + 151003136);    // 33,554,432 B (4x1024x4096)
  short* sc   = (short*)(ws);                // 67,108,864 B (2x4096x4096, over xf)

  // 1) fp32 -> f16 conversions
  cvt_f32_f16<<<16384, 256, 0, stream>>>(x, xf, 33554432);
  cvt_f32_f16<<<1024, 256, 0, stream>>>(thw, wcat, 2097152);
  cvt_f32_f16<<<1024, 256, 0, stream>>>(phw, wcat + 2097152, 2097152);
  cvt_f32_f16<<<1024, 256, 0, stream>>>(gw, gwb, 2097152);
  cvt_f32_f16<<<1024, 256, 0, stream>>>(Ww, wWb, 2097152);
  hipMemcpyAsync(bc, thb, 4096, hipMemcpyDeviceToDevice, stream);
  hipMemcpyAsync(bc + 1024, phb, 4096, hipMemcpyDeviceToDevice, stream);

  // 2) proj: [theta|phi] = x @ wcat^T + bias   (16384 x 2048, K=2048)
  gemmf<2048, 1, 1, 0><<<dim3(8, 64, 1), 256, 0, stream>>>(
      xf, 2048, 0L, wcat, 2048, 0L, tpf, 2048, 0L, bc, nullptr, 0L);

  // 3) gT[b] = g_w @ x_b^T + g_b[row]   (1024 x 4096 per batch, K=2048)
  gemmf<2048, 1, 2, 0><<<dim3(16, 4, 4), 256, 0, stream>>>(
      gwb, 2048, 0L, xf, 2048, 8388608L, gT, 4096, 4194304L, gbi, nullptr, 0L);

  // 4) per batch-PAIR p: scores(z=2) -> softmax -> y(z=2) -> z(z=2)
  //    sc pair overlays xf (dead after gT); y overwrites consumed theta/phi.
  for (int p = 0; p < 2; ++p) {
    const short* tp = tpf + (size_t)p * 16777216;
    gemmf<1024, 1, 0, 0><<<dim3(16, 16, 2), 256, 0, stream>>>(
        tp, 2048, 8388608L, tp + 1024, 2048, 8388608L,
        sc, 4096, 16777216L, nullptr, nullptr, 0L);
    softmax_rows<<<8192, 256, 0, stream>>>(sc);
    short* yp = tpf + (size_t)p * 16777216;  // pair-p theta/phi now dead
    gemmf<4096, 1, 0, 0><<<dim3(4, 16, 2), 256, 0, stream>>>(
        sc, 4096, 16777216L, gT + (size_t)p * 8388608, 4096, 4194304L,
        yp, 1024, 4194304L, nullptr, nullptr, 0L);
    gemmf<1024, 0, 1, 1><<<dim3(8, 16, 2), 256, 0, stream>>>(
        yp, 1024, 4194304L, wWb, 1024, 0L,
        out + (size_t)p * 16777216, 2048, 8388608L,
        Wb, x + (size_t)p * 16777216, 8388608L);
  }
}